// Round 1
// baseline (353.034 us; speedup 1.0000x reference)
//
#include <hip/hip_runtime.h>

// out[i] = sum_{e: rows[e]==i} Param_W[params[e]] * x[cols[e]] + Param_b[b_params[i]]
// N = 262144, E = 16777216, NPARAMS = 1280, NB = 16.
//
// R10: pipeline val and scan. Measured: val (~90-105us, vector-pipe/gather
// bound) and scan4 (107us, LDS ds_add bound: 3.1cyc/active-lane -> 85us floor)
// use DISJOINT pipes but ran serialized. Split E into halves; merged_kernel
// runs scan(H0) on warps 0-7 and val(H1) on warps 8-15 of the same block
// (no cross-block sync; dependency via kernel boundaries). Merged val role
// gathers PW from global/L1 (5KB) to keep the LDS pipe free for ds_adds.
// Predict: val(H0)~47 + merged~65 + scan4(H1)~53 + reduce~6 ~= 170-195 sum.

#define SLICE_BITS  15
#define SLICE_SIZE  (1 << SLICE_BITS)   // 32768
#define SLICES      8
#define CHUNKS      32                  // chunks per scan launch (per half in split mode)
#define NPARAMS_MAX 2048
#define SCAN_THREADS 1024
#define SB4         4                   // int4-groups per ping-pong buffer
#define VB          4                   // batched groups per val-kernel thread
#define M_SCAN_T    512                 // merged kernel: scan warps 0-7
#define M_VAL_T     512                 // merged kernel: val warps 8-15
#define M_THREADS   1024

typedef float v4f __attribute__((ext_vector_type(4)));

// ---------------- Kernel V: val precompute (streaming) ----------------
__global__ __launch_bounds__(256) void val_kernel(
    const float* __restrict__ x, const float* __restrict__ PW, int nparams,
    const int4* __restrict__ cols4, const int4* __restrict__ params4,
    v4f* __restrict__ vals4)
{
    __shared__ float pw[NPARAMS_MAX];
    for (int j = threadIdx.x; j < nparams; j += 256) pw[j] = PW[j];
    __syncthreads();
    const int base = blockIdx.x * (256 * VB) + threadIdx.x;
    int4 c[VB], p[VB];
#pragma unroll
    for (int k = 0; k < VB; ++k) {
        c[k] = cols4[base + k * 256];     // cached loads (nt loads regressed in R8)
        p[k] = params4[base + k * 256];
    }
#pragma unroll
    for (int k = 0; k < VB; ++k) {
        v4f v;
        v.x = pw[p[k].x] * x[c[k].x];
        v.y = pw[p[k].y] * x[c[k].y];
        v.z = pw[p[k].z] * x[c[k].z];
        v.w = pw[p[k].w] * x[c[k].w];
        // nontemporal: don't let the val stream evict x (1 MB) from L2
        __builtin_nontemporal_store(v, &vals4[base + k * 256]);
    }
}

// ------- Kernel S: 2-stream scan, ping-pong prefetch + predicated adds -------
__global__ __launch_bounds__(SCAN_THREADS, 1) void scan4_kernel(
    const int4* __restrict__ rows4, const float4* __restrict__ vals4,
    float* __restrict__ partials, int e4_per_chunk, int accumulate)
{
    __shared__ float acc[SLICE_SIZE];    // 128 KiB -> 1 block/CU
    const int bid = blockIdx.x;
    const int s = bid / CHUNKS;          // slice
    const int c = bid % CHUNKS;          // chunk; bid%8 == c%8 -> the 8 readers of a
                                         // chunk co-locate on one XCD (round-robin)
    for (int j = threadIdx.x; j < SLICE_SIZE; j += SCAN_THREADS) acc[j] = 0.0f;
    __syncthreads();

    const int4*   rp = rows4 + (size_t)c * e4_per_chunk;
    const float4* vp = vals4 + (size_t)c * e4_per_chunk;
    const int per_thread = e4_per_chunk / SCAN_THREADS;

    int4   rA[SB4], rB[SB4];
    float4 vA[SB4], vB[SB4];

#define LOAD(dstR, dstV, b0)                                             \
    _Pragma("unroll")                                                    \
    for (int b = 0; b < SB4; ++b) {                                      \
        const int g = ((b0) + b) * SCAN_THREADS + (int)threadIdx.x;      \
        dstR[b] = rp[g];                                                 \
        dstV[b] = vp[g];                                                 \
    }
#define PROC(rX, vX)                                                     \
    _Pragma("unroll")                                                    \
    for (int b = 0; b < SB4; ++b) {                                      \
        if ((rX[b].x >> SLICE_BITS) == s) atomicAdd(&acc[rX[b].x & (SLICE_SIZE - 1)], vX[b].x); \
        if ((rX[b].y >> SLICE_BITS) == s) atomicAdd(&acc[rX[b].y & (SLICE_SIZE - 1)], vX[b].y); \
        if ((rX[b].z >> SLICE_BITS) == s) atomicAdd(&acc[rX[b].z & (SLICE_SIZE - 1)], vX[b].z); \
        if ((rX[b].w >> SLICE_BITS) == s) atomicAdd(&acc[rX[b].w & (SLICE_SIZE - 1)], vX[b].w); \
    }

    LOAD(rA, vA, 0)
    for (int base = 0; base < per_thread; base += 2 * SB4) {
        LOAD(rB, vB, base + SB4)           // in flight while A's atomics issue
        PROC(rA, vA)
        if (base + 2 * SB4 < per_thread) {
            LOAD(rA, vA, base + 2 * SB4)   // in flight while B's atomics issue
        }
        PROC(rB, vB)
    }
#undef LOAD
#undef PROC
    __syncthreads();

    float* dst = partials + (size_t)bid * SLICE_SIZE;
    if (accumulate) {
        for (int j = threadIdx.x; j < SLICE_SIZE; j += SCAN_THREADS) dst[j] += acc[j];
    } else {
        for (int j = threadIdx.x; j < SLICE_SIZE; j += SCAN_THREADS) dst[j] = acc[j];
    }
}

// ----- Kernel M: merged scan(H0) [warps 0-7] + val(H1) [warps 8-15] -----
// One block per CU (128 KiB LDS). Scan role is LDS-atomic-pipe bound
// (~42us); val role is vector-pipe bound (~45us); they overlap inside the
// block. Val role reads PW via global (L1-resident, 5KB) so its gathers
// stay OFF the LDS pipe the scan needs.
__global__ __launch_bounds__(M_THREADS, 1) void merged_kernel(
    const int4* __restrict__ rows4, const float4* __restrict__ vals4,
    float* __restrict__ partials, int e4_per_chunk,
    const float* __restrict__ x, const float* __restrict__ PW,
    const int4* __restrict__ cols4v, const int4* __restrict__ params4v,
    v4f* __restrict__ vals4v, int vpt)
{
    __shared__ float acc[SLICE_SIZE];    // 128 KiB
    const int bid = blockIdx.x;
    const int s = bid / CHUNKS;
    const int c = bid % CHUNKS;
    for (int j = threadIdx.x; j < SLICE_SIZE; j += M_THREADS) acc[j] = 0.0f;
    __syncthreads();

    if (threadIdx.x < M_SCAN_T) {
        // ---- scan role: chunk c of half 0 ----
        const int4*   rp = rows4 + (size_t)c * e4_per_chunk;
        const float4* vp = vals4 + (size_t)c * e4_per_chunk;
        const int per_thread = e4_per_chunk / M_SCAN_T;

        int4   rA[SB4], rB[SB4];
        float4 vA[SB4], vB[SB4];

#define MLOAD(dstR, dstV, b0)                                            \
    _Pragma("unroll")                                                    \
    for (int b = 0; b < SB4; ++b) {                                      \
        const int g = ((b0) + b) * M_SCAN_T + (int)threadIdx.x;          \
        dstR[b] = rp[g];                                                 \
        dstV[b] = vp[g];                                                 \
    }
#define MPROC(rX, vX)                                                    \
    _Pragma("unroll")                                                    \
    for (int b = 0; b < SB4; ++b) {                                      \
        if ((rX[b].x >> SLICE_BITS) == s) atomicAdd(&acc[rX[b].x & (SLICE_SIZE - 1)], vX[b].x); \
        if ((rX[b].y >> SLICE_BITS) == s) atomicAdd(&acc[rX[b].y & (SLICE_SIZE - 1)], vX[b].y); \
        if ((rX[b].z >> SLICE_BITS) == s) atomicAdd(&acc[rX[b].z & (SLICE_SIZE - 1)], vX[b].z); \
        if ((rX[b].w >> SLICE_BITS) == s) atomicAdd(&acc[rX[b].w & (SLICE_SIZE - 1)], vX[b].w); \
    }

        MLOAD(rA, vA, 0)
        for (int base = 0; base < per_thread; base += 2 * SB4) {
            MLOAD(rB, vB, base + SB4)
            MPROC(rA, vA)
            if (base + 2 * SB4 < per_thread) {
                MLOAD(rA, vA, base + 2 * SB4)
            }
            MPROC(rB, vB)
        }
#undef MLOAD
#undef MPROC
    } else {
        // ---- val role: 1/256 stripe of half 1 ----
        const int vtid = (int)threadIdx.x - M_SCAN_T;
        const size_t blockBase = (size_t)bid * vpt * M_VAL_T;
        for (int k = 0; k < vpt; k += 4) {
            int4 cc[4], pp[4];
#pragma unroll
            for (int u = 0; u < 4; ++u) {
                const size_t g = blockBase + (size_t)(k + u) * M_VAL_T + vtid;
                cc[u] = cols4v[g];
                pp[u] = params4v[g];
            }
#pragma unroll
            for (int u = 0; u < 4; ++u) {
                const size_t g = blockBase + (size_t)(k + u) * M_VAL_T + vtid;
                v4f v;
                v.x = PW[pp[u].x] * x[cc[u].x];
                v.y = PW[pp[u].y] * x[cc[u].y];
                v.z = PW[pp[u].z] * x[cc[u].z];
                v.w = PW[pp[u].w] * x[cc[u].w];
                __builtin_nontemporal_store(v, &vals4v[g]);
            }
        }
    }
    __syncthreads();

    float* dst = partials + (size_t)bid * SLICE_SIZE;
    for (int j = threadIdx.x; j < SLICE_SIZE; j += M_THREADS) dst[j] = acc[j];
}

// ---------------- Kernel E: reduce partials + bias ----------------
__global__ __launch_bounds__(256) void reduce_bias_kernel(
    const float* __restrict__ partials, const float* __restrict__ Pb,
    const int* __restrict__ bp, float* __restrict__ out, int n)
{
    const int i = blockIdx.x * 256 + threadIdx.x;
    if (i >= n) return;
    const int s = i >> SLICE_BITS;
    const int j = i & (SLICE_SIZE - 1);
    const float* p = partials + ((size_t)s * CHUNKS) * SLICE_SIZE + j;
    float sum = 0.0f;
#pragma unroll
    for (int g = 0; g < CHUNKS; ++g) sum += p[(size_t)g * SLICE_SIZE];
    out[i] = sum + Pb[bp[i]];
}

// ---------------- fallback: R3 slice-scan (3-stream) ----------------
#define FB_BATCH 4
__global__ __launch_bounds__(SCAN_THREADS, 1) void slice_scan_kernel(
    const float* __restrict__ x, const float* __restrict__ PW, int nparams,
    const int4* __restrict__ rows4, const int4* __restrict__ cols4,
    const int4* __restrict__ params4, float* __restrict__ partials,
    int e4_per_chunk)
{
    __shared__ float acc[SLICE_SIZE];
    __shared__ float pw_lds[NPARAMS_MAX];
    const int bid = blockIdx.x;
    const int s = bid / CHUNKS;
    const int c = bid % CHUNKS;
    for (int j = threadIdx.x; j < SLICE_SIZE; j += SCAN_THREADS) acc[j] = 0.0f;
    for (int j = threadIdx.x; j < nparams; j += SCAN_THREADS) pw_lds[j] = PW[j];
    __syncthreads();
    const int4* rp = rows4   + (size_t)c * e4_per_chunk;
    const int4* cp = cols4   + (size_t)c * e4_per_chunk;
    const int4* qp = params4 + (size_t)c * e4_per_chunk;
    const int per_thread = e4_per_chunk / SCAN_THREADS;
    for (int base = 0; base < per_thread; base += FB_BATCH) {
        int4 r[FB_BATCH], cc[FB_BATCH], pp[FB_BATCH];
#pragma unroll
        for (int b = 0; b < FB_BATCH; ++b) {
            const int g = (base + b) * SCAN_THREADS + threadIdx.x;
            r[b] = rp[g]; cc[b] = cp[g]; pp[b] = qp[g];
        }
#pragma unroll
        for (int b = 0; b < FB_BATCH; ++b) {
            if ((r[b].x >> SLICE_BITS) == s)
                atomicAdd(&acc[r[b].x & (SLICE_SIZE - 1)], pw_lds[pp[b].x] * x[cc[b].x]);
            if ((r[b].y >> SLICE_BITS) == s)
                atomicAdd(&acc[r[b].y & (SLICE_SIZE - 1)], pw_lds[pp[b].y] * x[cc[b].y]);
            if ((r[b].z >> SLICE_BITS) == s)
                atomicAdd(&acc[r[b].z & (SLICE_SIZE - 1)], pw_lds[pp[b].z] * x[cc[b].z]);
            if ((r[b].w >> SLICE_BITS) == s)
                atomicAdd(&acc[r[b].w & (SLICE_SIZE - 1)], pw_lds[pp[b].w] * x[cc[b].w]);
        }
    }
    __syncthreads();
    float* dst = partials + (size_t)bid * SLICE_SIZE;
    for (int j = threadIdx.x; j < SLICE_SIZE; j += SCAN_THREADS) dst[j] = acc[j];
}

__global__ __launch_bounds__(256) void bias_init_kernel(const float* __restrict__ Pb,
                                                        const int* __restrict__ bp,
                                                        float* __restrict__ out, int n) {
    int i = blockIdx.x * 256 + threadIdx.x;
    if (i < n) out[i] = Pb[bp[i]];
}

__global__ __launch_bounds__(256) void edge_scatter_kernel(const float* __restrict__ x,
                                                           const float* __restrict__ PW,
                                                           const int* __restrict__ rows,
                                                           const int* __restrict__ cols,
                                                           const int* __restrict__ params,
                                                           float* __restrict__ out, int E) {
    int e = blockIdx.x * 256 + threadIdx.x;
    if (e < E) atomicAdd(out + rows[e], PW[params[e]] * x[cols[e]]);
}

extern "C" void kernel_launch(void* const* d_in, const int* in_sizes, int n_in,
                              void* d_out, int out_size, void* d_ws, size_t ws_size,
                              hipStream_t stream) {
    const float* x        = (const float*)d_in[0];
    const float* Param_W  = (const float*)d_in[1];
    const float* Param_b  = (const float*)d_in[2];
    const int*   w_rows   = (const int*)d_in[3];
    const int*   w_cols   = (const int*)d_in[4];
    const int*   w_params = (const int*)d_in[5];
    const int*   b_params = (const int*)d_in[6];
    float* out = (float*)d_out;

    const int N_  = in_sizes[0];   // 262144
    const int NP_ = in_sizes[1];   // 1280
    const int E_  = in_sizes[3];   // 16777216
    const int e4  = E_ / 4;
    const int e4h = e4 / 2;

    const size_t partial_bytes = (size_t)SLICES * CHUNKS * SLICE_SIZE * sizeof(float); // 32 MiB
    const size_t vals_bytes    = (size_t)E_ * sizeof(float);                            // 64 MiB

    const bool base_ok = (N_ == SLICES * SLICE_SIZE) && (NP_ <= NPARAMS_MAX);

    // ---- split/pipelined path shape checks ----
    bool split_ok = base_ok && (E_ % 8 == 0) && (e4h % CHUNKS == 0) &&
                    (e4h % (256 * VB) == 0);
    const int e4c_h = split_ok ? (e4h / CHUNKS) : 0;
    const int vpt   = split_ok ? (e4h / (256 * M_VAL_T)) : 0;
    split_ok = split_ok &&
               (e4c_h % (M_SCAN_T * 2 * SB4) == 0) &&        // merged scan role
               (e4c_h % (SCAN_THREADS * 2 * SB4) == 0) &&    // scan4 on half 1
               (vpt > 0) && (vpt % 4 == 0) &&
               ((size_t)256 * M_VAL_T * vpt == (size_t)e4h); // merged val covers H1 exactly

    // ---- full (unsplit) path shape checks (R9 behavior) ----
    const bool full_ok = base_ok && (E_ % (4 * 256 * VB) == 0) &&
                         (E_ % (4 * CHUNKS * SCAN_THREADS * 2 * SB4) == 0);

    if (split_ok && ws_size >= vals_bytes + partial_bytes) {
        float* vals     = (float*)d_ws;
        float* partials = (float*)((char*)d_ws + vals_bytes);

        // 1) vals for half 0
        val_kernel<<<e4h / (256 * VB), 256, 0, stream>>>(
            x, Param_W, NP_, (const int4*)w_cols, (const int4*)w_params, (v4f*)vals);
        // 2) scan(H0) overlapped with val(H1)
        merged_kernel<<<SLICES * CHUNKS, M_THREADS, 0, stream>>>(
            (const int4*)w_rows, (const float4*)vals, partials, e4c_h,
            x, Param_W,
            (const int4*)w_cols + e4h, (const int4*)w_params + e4h,
            (v4f*)vals + e4h, vpt);
        // 3) scan(H1), accumulate into partials
        scan4_kernel<<<SLICES * CHUNKS, SCAN_THREADS, 0, stream>>>(
            (const int4*)w_rows + e4h, (const float4*)vals + e4h, partials, e4c_h, 1);
        // 4) reduce + bias
        reduce_bias_kernel<<<(N_ + 255) / 256, 256, 0, stream>>>(
            partials, Param_b, b_params, out, N_);
    } else if (full_ok && ws_size >= vals_bytes + partial_bytes) {
        float*  vals     = (float*)d_ws;
        float*  partials = (float*)((char*)d_ws + vals_bytes);
        const int e4_per_chunk = e4 / CHUNKS;
        val_kernel<<<e4 / (256 * VB), 256, 0, stream>>>(
            x, Param_W, NP_, (const int4*)w_cols, (const int4*)w_params, (v4f*)vals);
        scan4_kernel<<<SLICES * CHUNKS, SCAN_THREADS, 0, stream>>>(
            (const int4*)w_rows, (const float4*)vals, partials, e4_per_chunk, 0);
        reduce_bias_kernel<<<(N_ + 255) / 256, 256, 0, stream>>>(
            partials, Param_b, b_params, out, N_);
    } else if (base_ok && (E_ % (4 * CHUNKS * SCAN_THREADS * FB_BATCH) == 0) &&
               ws_size >= partial_bytes) {
        float* partials = (float*)d_ws;
        const int e4_per_chunk = e4 / CHUNKS;
        slice_scan_kernel<<<SLICES * CHUNKS, SCAN_THREADS, 0, stream>>>(
            x, Param_W, NP_, (const int4*)w_rows, (const int4*)w_cols,
            (const int4*)w_params, partials, e4_per_chunk);
        reduce_bias_kernel<<<(N_ + 255) / 256, 256, 0, stream>>>(
            partials, Param_b, b_params, out, N_);
    } else {
        bias_init_kernel<<<(N_ + 255) / 256, 256, 0, stream>>>(Param_b, b_params, out, N_);
        edge_scatter_kernel<<<(E_ + 255) / 256, 256, 0, stream>>>(
            x, Param_W, w_rows, w_cols, w_params, out, E_);
    }
}